// Round 10
// baseline (376.746 us; speedup 1.0000x reference)
//
#include <hip/hip_runtime.h>

#define TLEN 512
#define HD 128
#define VOC 50000

typedef float fvec4 __attribute__((ext_vector_type(4)));   // f32 MFMA accumulator
typedef int   ivec4 __attribute__((ext_vector_type(4)));   // 16B LDS read
typedef int   ivec8 __attribute__((ext_vector_type(8)));   // 32 fp8 = f8f6f4 operand

__device__ __forceinline__ float fsig(float a){
  return __builtin_amdgcn_rcpf(1.f + __builtin_amdgcn_exp2f(-1.44269504f * a));
}

// ---------------- emb fp32 -> fp8 e4m3 (x16 scale) table ----------------
__global__ void emb_cvt8(const float* __restrict__ emb, int* __restrict__ out, int n4){
  int i = blockIdx.x * blockDim.x + threadIdx.x;
  if (i < n4){
    float4 v = *(const float4*)(emb + (size_t)i * 4);
    int p = __builtin_amdgcn_cvt_pk_fp8_f32(16.f * v.x, 16.f * v.y, 0, 0);
    p     = __builtin_amdgcn_cvt_pk_fp8_f32(16.f * v.z, 16.f * v.w, p, 1);
    out[i] = p;
  }
}

// ---------------- persistent bidirectional GRU scan: 4-wave all-fp8, 2 blocks/CU ----------------
// 512 blocks: 0..255 fwd, 256..511 bwd; 2 batches each; 256 threads = 4 waves.
// LDS claim = 80KB exactly -> 2 blocks/CU with INDEPENDENT barriers: while one
// block's wave sits in its serial-chain latency (ds_read -> MFS -> gate), the
// co-resident block's wave issues. Register-dieted vs round 9 (single xp acc set
// rebuilt at step 3, 1-group x prefetch, splat-on-use biases) so the unified
// VGPR+acc footprint fits the 2-waves/SIMD band (<=256).
// Batches at tile rows {0,4}; rows 8..15 duplicate them (bounded copies).
// Both x@W (4 steps packed/tile) and h@U use mfma_scale 16x16x128 fp8, all
// operands stored x16 with e8m0 block-scale 2^-4 per side (exact net 1).
__global__ __launch_bounds__(256, 1) void gru_scan(
    const int* __restrict__ tokens, const unsigned char* __restrict__ embq,
    const float* __restrict__ Wf, const float* __restrict__ Uf, const float* __restrict__ bfv,
    const float* __restrict__ Wb, const float* __restrict__ Ub, const float* __restrict__ bbv,
    float* __restrict__ hbuf)
{
  const int tid  = threadIdx.x;
  const int wid  = tid >> 6, lane = tid & 63;
  const int l15  = lane & 15, l4 = lane >> 4;
  const int dir  = blockIdx.x >> 8, grp = blockIdx.x & 255;
  const int c0   = wid * 32 + 2 * l15, c1 = c0 + 1;   // owned gate columns

  const float* __restrict__ W  = dir ? Wb : Wf;
  const float* __restrict__ U  = dir ? Ub : Uf;
  const float* __restrict__ bv = dir ? bbv : bfv;

  // exactly 80KB -> 2 blocks/CU (2 x 81920 = 160 KiB). Used: 8KB h fp8 dbuf.
  __shared__ __attribute__((aligned(16))) unsigned char hl[81920];

  // fp8 B-frags (x16): lane (l4,l15): col = chosen, k = l4*32 + j
  auto pack8 = [&](const float* M, int col)->ivec8{
    ivec8 q;
#pragma unroll
    for (int w = 0; w < 8; ++w){
      const int k0 = l4 * 32 + w * 4;
      int v = __builtin_amdgcn_cvt_pk_fp8_f32(16.f*M[(k0+0)*384 + col], 16.f*M[(k0+1)*384 + col], 0, 0);
      q[w]  = __builtin_amdgcn_cvt_pk_fp8_f32(16.f*M[(k0+2)*384 + col], 16.f*M[(k0+3)*384 + col], v, 1);
    }
    return q;
  };
  const ivec8 Qz0 = pack8(U, c0), Qr0 = pack8(U, 128 + c0), Qh0 = pack8(U, 256 + c0);
  const ivec8 Qz1 = pack8(U, c1), Qr1 = pack8(U, 128 + c1), Qh1 = pack8(U, 256 + c1);
  const ivec8 Pz0 = pack8(W, c0), Pr0 = pack8(W, 128 + c0), Ph0 = pack8(W, 256 + c0);
  const ivec8 Pz1 = pack8(W, c1), Pr1 = pack8(W, 128 + c1), Ph1 = pack8(W, 256 + c1);

  // biases: z/r (bi+bh) and hh-input folded into xp C (splat on use); hh-recurrent in gate
  const float bz0 = bv[c0] + bv[384 + c0], br0 = bv[128 + c0] + bv[384 + 128 + c0];
  const float bx0 = bv[256 + c0],          bu0 = bv[384 + 256 + c0];
  const float bz1 = bv[c1] + bv[384 + c1], br1 = bv[128 + c1] + bv[384 + 128 + c1];
  const float bx1 = bv[256 + c1],          bu1 = bv[384 + 256 + c1];
  const fvec4 ZF  = {0.f,0.f,0.f,0.f};
#define SP4(b) ((fvec4){(b),(b),(b),(b)})

  for (int i = tid; i < 2048; i += 256) ((int*)hl)[i] = 0;   // zero both h buffers
  float h0a = 0.f, h0b = 0.f;        // h[batch][c0], h[batch][c1] fp32 master

  // x A-frag: tile row l15 = (batch (l15>>2)&1, step l15&3); rows 8..15 duplicate
  const int  brow = (l15 >> 2) & 1, srow = l15 & 3;
  const long tbx  = (long)(grp * 2 + brow) * TLEN;
  const int  tb0  = dir ? (TLEN - 1) : 0, tsg = dir ? -1 : 1;
  auto tix = [&](int t){ t = (t > TLEN - 1) ? (TLEN - 1) : t; return tb0 + tsg * t; };
#define XLD(tok) (*(const ivec8*)(embq + (size_t)(tok) * HD + l4 * 32))
#define MFS(A, B, C) __builtin_amdgcn_mfma_scale_f32_16x16x128_f8f6f4(A, B, C, 0, 0, 0, 0x7B7B7B7B, 0, 0x7B7B7B7B)

  // xp accumulators (single set; rebuilt in step 3 of each group)
  fvec4 xZ0, xR0, xX0, xZ1, xR1, xX1;
  ivec8 xfa;
  {
    const int t0 = tokens[tbx + tix(srow)];
    ivec8 xf0 = XLD(t0);
    xZ0 = MFS(xf0, Pz0, SP4(bz0)); xR0 = MFS(xf0, Pr0, SP4(br0)); xX0 = MFS(xf0, Ph0, SP4(bx0));
    xZ1 = MFS(xf0, Pz1, SP4(bz1)); xR1 = MFS(xf0, Pr1, SP4(br1)); xX1 = MFS(xf0, Ph1, SP4(bx1));
    xfa = XLD(tokens[tbx + tix(4 + srow)]);
  }
  int tok2 = tokens[tbx + tix(8 + srow)];

  const int hrd = l15 * 144 + l4 * 32;                 // h A-frag base (byte)
  const int wb  = (4 * l4) * 144 + c0;                 // b16 h write slot (byte)
  __syncthreads();

#define STEP(S, P, XTRA) { \
    ivec4 alo = *(const ivec4*)&hl[(P) + hrd]; \
    ivec4 ahi = *(const ivec4*)&hl[(P) + hrd + 16]; \
    ivec8 af = __builtin_shufflevector(alo, ahi, 0,1,2,3,4,5,6,7); \
    fvec4 aZ0 = MFS(af, Qz0, ZF); \
    fvec4 aR0 = MFS(af, Qr0, ZF); \
    fvec4 aU0 = MFS(af, Qh0, ZF); \
    fvec4 aZ1 = MFS(af, Qz1, ZF); \
    fvec4 aR1 = MFS(af, Qr1, ZF); \
    fvec4 aU1 = MFS(af, Qh1, ZF); \
    float z0 = fsig(xZ0[S] + aZ0[0]); \
    float r0 = fsig(xR0[S] + aR0[0]); \
    float a0 = xX0[S] + r0 * (aU0[0] + bu0); a0 = fmaxf(a0, -30.f); \
    float y0 = __builtin_amdgcn_exp2f(-2.88539008f * a0); \
    float t0 = (1.f - y0) * __builtin_amdgcn_rcpf(1.f + y0); \
    h0a = t0 + z0 * (h0a - t0); \
    float z1 = fsig(xZ1[S] + aZ1[0]); \
    float r1 = fsig(xR1[S] + aR1[0]); \
    float a1 = xX1[S] + r1 * (aU1[0] + bu1); a1 = fmaxf(a1, -30.f); \
    float y1 = __builtin_amdgcn_exp2f(-2.88539008f * a1); \
    float t1 = (1.f - y1) * __builtin_amdgcn_rcpf(1.f + y1); \
    h0b = t1 + z1 * (h0b - t1); \
    *(unsigned short*)&hl[((P) ^ 4096) + wb] = \
        (unsigned short)(__builtin_amdgcn_cvt_pk_fp8_f32(16.f * h0a, 16.f * h0b, 0, 0) & 0xffff); \
    XTRA \
    asm volatile("s_waitcnt lgkmcnt(0)" ::: "memory"); \
    __builtin_amdgcn_s_barrier(); \
}

  for (int g = 0; g < 128; ++g){
    STEP(0, 0,    { })
    STEP(1, 4096, { })
    STEP(2, 0,    { })
    // step 3: after the h-write, rebuild xp accs for group g+1 (register-only,
    // sits between ds_write and barrier -> doesn't lengthen the serial chain),
    // then issue the x prefetch for group g+2.
    STEP(3, 4096, {
      xZ0 = MFS(xfa, Pz0, SP4(bz0)); xR0 = MFS(xfa, Pr0, SP4(br0)); xX0 = MFS(xfa, Ph0, SP4(bx0));
      xZ1 = MFS(xfa, Pz1, SP4(bz1)); xR1 = MFS(xfa, Pr1, SP4(br1)); xX1 = MFS(xfa, Ph1, SP4(bx1));
      xfa = XLD(tok2);
      tok2 = tokens[tbx + tix(4 * (g + 3) + srow)];
    })
  }
#undef STEP
#undef MFS
#undef XLD
#undef SP4

  // final state: lanes l4<2 hold the real batches (tile rows 0,4)
  if (l4 < 2){
    hbuf[(size_t)(grp * 2 + l4) * 256 + dir * 128 + c0] = h0a;
    hbuf[(size_t)(grp * 2 + l4) * 256 + dir * 128 + c1] = h0b;
  }
}

// ---------------- head: sigmoid(hcat @ Wd + bd) ----------------
__global__ void head_k(const float* __restrict__ hbuf, const float* __restrict__ Wd,
                       const float* __restrict__ bd, float* __restrict__ out){
  const int wid = threadIdx.x >> 6, lane = threadIdx.x & 63;
  const int b = blockIdx.x * 4 + wid;
  const float* hr = hbuf + (size_t)b * 256;
  float s = 0.f;
#pragma unroll
  for (int j = 0; j < 4; ++j){ const int k = j * 64 + lane; s += hr[k] * Wd[k]; }
#pragma unroll
  for (int off = 32; off > 0; off >>= 1) s += __shfl_down(s, off);
  if (lane == 0) out[b] = 1.f / (1.f + __expf(-(s + bd[0])));
}

extern "C" void kernel_launch(void* const* d_in, const int* in_sizes, int n_in,
                              void* d_out, int out_size, void* d_ws, size_t ws_size,
                              hipStream_t stream){
  const int*   tokens = (const int*)  d_in[0];
  const float* emb    = (const float*)d_in[1];
  const float* Wf     = (const float*)d_in[2];
  const float* Uf     = (const float*)d_in[3];
  const float* bf_    = (const float*)d_in[4];
  const float* Wb     = (const float*)d_in[5];
  const float* Ub     = (const float*)d_in[6];
  const float* bb_    = (const float*)d_in[7];
  const float* Wd     = (const float*)d_in[8];
  const float* bd     = (const float*)d_in[9];
  float* out = (float*)d_out;

  unsigned char* embq = (unsigned char*)d_ws;                        // 6.4 MB fp8 table
  float* hbuf = (float*)((char*)d_ws + (size_t)VOC * HD);            // 512 KB

  const int n4 = VOC * HD / 4;
  emb_cvt8<<<(n4 + 255) / 256, 256, 0, stream>>>(emb, (int*)embq, n4);
  gru_scan<<<512, 256, 0, stream>>>(tokens, embq, Wf, Uf, bf_, Wb, Ub, bb_, hbuf);
  head_k<<<128, 256, 0, stream>>>(hbuf, Wd, bd, out);
}

// Round 11
// 177.022 us; speedup vs baseline: 2.1282x; 2.1282x over previous
//
#include <hip/hip_runtime.h>

#define TLEN 512
#define HD 128
#define VOC 50000

typedef float fvec4 __attribute__((ext_vector_type(4)));   // f32 MFMA accumulator
typedef int   ivec4 __attribute__((ext_vector_type(4)));   // 16B LDS read
typedef int   ivec8 __attribute__((ext_vector_type(8)));   // 32 fp8 = f8f6f4 operand

__device__ __forceinline__ float fsig(float a){
  return __builtin_amdgcn_rcpf(1.f + __builtin_amdgcn_exp2f(-1.44269504f * a));
}

// ---------------- emb fp32 -> fp8 e4m3 (x16 scale) table ----------------
__global__ void emb_cvt8(const float* __restrict__ emb, int* __restrict__ out, int n4){
  int i = blockIdx.x * blockDim.x + threadIdx.x;
  if (i < n4){
    float4 v = *(const float4*)(emb + (size_t)i * 4);
    int p = __builtin_amdgcn_cvt_pk_fp8_f32(16.f * v.x, 16.f * v.y, 0, 0);
    p     = __builtin_amdgcn_cvt_pk_fp8_f32(16.f * v.z, 16.f * v.w, p, 1);
    out[i] = p;
  }
}

// ---------------- persistent bidirectional GRU scan: 8-wave x 1 col-tile ----------------
// 256 blocks = 256 CUs (96KB LDS pin): 0..127 fwd, 128..255 bwd; 4 batches each
// (tile rows 0,4,8,12). 512 threads = 8 waves; wave w owns gate cols [w*16,w*16+16).
// Rationale (r10 lesson): wall time = 512 x per-chain STEP LATENCY; co-residency
// can't cut it. So halve the serial step path instead: per wave per step only
// 3 K=128 fp8 MFS (was 6), 1 gate per lane (was 2), 1-byte h write, 2 ds_read_b128.
// All fp8 stored x16 with e8m0 block-scale 2^-4 per side (exact net 1).
// xp (x@W+bi, 4 steps packed as A-rows) woven at step 3 after gate extraction.
__global__ __launch_bounds__(512, 2) void gru_scan(
    const int* __restrict__ tokens, const unsigned char* __restrict__ embq,
    const float* __restrict__ Wf, const float* __restrict__ Uf, const float* __restrict__ bfv,
    const float* __restrict__ Wb, const float* __restrict__ Ub, const float* __restrict__ bbv,
    float* __restrict__ hbuf)
{
  const int tid  = threadIdx.x;
  const int wid  = tid >> 6, lane = tid & 63;
  const int l15  = lane & 15, l4 = lane >> 4;
  const int dir  = blockIdx.x >> 7, grp = blockIdx.x & 127;
  const int c    = wid * 16 + l15;                   // this lane's single gate column

  const float* __restrict__ W  = dir ? Wb : Wf;
  const float* __restrict__ U  = dir ? Ub : Uf;
  const float* __restrict__ bv = dir ? bbv : bfv;

  // claim 96KB -> 1 block/CU; used: 8KB h fp8 dbuf (16 rows x 144B at 0 / 4096)
  __shared__ __attribute__((aligned(16))) unsigned char hl[98304];

  // fp8 B-frags (x16): lane (l4,l15): col = chosen, k = l4*32 + j
  auto pack8 = [&](const float* M, int col)->ivec8{
    ivec8 q;
#pragma unroll
    for (int w = 0; w < 8; ++w){
      const int k0 = l4 * 32 + w * 4;
      int v = __builtin_amdgcn_cvt_pk_fp8_f32(16.f*M[(k0+0)*384 + col], 16.f*M[(k0+1)*384 + col], 0, 0);
      q[w]  = __builtin_amdgcn_cvt_pk_fp8_f32(16.f*M[(k0+2)*384 + col], 16.f*M[(k0+3)*384 + col], v, 1);
    }
    return q;
  };
  const ivec8 Qz = pack8(U, c), Qr = pack8(U, 128 + c), Qh = pack8(U, 256 + c);
  const ivec8 Pz = pack8(W, c), Pr = pack8(W, 128 + c), Ph = pack8(W, 256 + c);

  // biases: z/r (bi+bh) and hh-input folded into xp C (splat on use); hh-recurrent in gate
  const float bz = bv[c] + bv[384 + c];
  const float br = bv[128 + c] + bv[384 + 128 + c];
  const float bx = bv[256 + c];
  const float bu = bv[384 + 256 + c];
  const fvec4 ZF = {0.f,0.f,0.f,0.f};
#define SP4(b) ((fvec4){(b),(b),(b),(b)})

  for (int i = tid; i < 2048; i += 512) ((int*)hl)[i] = 0;   // zero both h buffers
  float h0 = 0.f;                                   // h[batch l4][c] fp32 master

  // x A-frag: tile row l15 = (batch l15>>2, step l15&3)
  const int  brow = l15 >> 2, srow = l15 & 3;
  const long tbx  = (long)(grp * 4 + brow) * TLEN;
  const int  tb0  = dir ? (TLEN - 1) : 0, tsg = dir ? -1 : 1;
  auto tix = [&](int t){ t = (t > TLEN - 1) ? (TLEN - 1) : t; return tb0 + tsg * t; };
#define XLD(tok) (*(const ivec8*)(embq + (size_t)(tok) * HD + l4 * 32))
#define MFS(A, B, C) __builtin_amdgcn_mfma_scale_f32_16x16x128_f8f6f4(A, B, C, 0, 0, 0, 0x7B7B7B7B, 0, 0x7B7B7B7B)

  // xp accumulators (single set; rebuilt at step 3 after gate extraction)
  fvec4 xZ, xR, xX;
  ivec8 xfa;
  {
    const int t0 = tokens[tbx + tix(srow)];
    ivec8 xf0 = XLD(t0);
    xZ = MFS(xf0, Pz, SP4(bz)); xR = MFS(xf0, Pr, SP4(br)); xX = MFS(xf0, Ph, SP4(bx));
    xfa = XLD(tokens[tbx + tix(4 + srow)]);
  }
  int tok2 = tokens[tbx + tix(8 + srow)];

  const int hrd = l15 * 144 + l4 * 32;               // h A-frag base (byte)
  const int wb  = (4 * l4) * 144 + c;                // 1-byte h write slot

  __syncthreads();

#define STEP(S, P, XTRA) { \
    ivec4 alo = *(const ivec4*)&hl[(P) + hrd]; \
    ivec4 ahi = *(const ivec4*)&hl[(P) + hrd + 16]; \
    ivec8 af = __builtin_shufflevector(alo, ahi, 0,1,2,3,4,5,6,7); \
    fvec4 aZ = MFS(af, Qz, ZF); \
    fvec4 aR = MFS(af, Qr, ZF); \
    fvec4 aU = MFS(af, Qh, ZF); \
    float z = fsig(xZ[S] + aZ[0]); \
    float r = fsig(xR[S] + aR[0]); \
    float a = xX[S] + r * (aU[0] + bu); a = fmaxf(a, -30.f); \
    float y = __builtin_amdgcn_exp2f(-2.88539008f * a); \
    float th = (1.f - y) * __builtin_amdgcn_rcpf(1.f + y); \
    h0 = th + z * (h0 - th); \
    hl[((P) ^ 4096) + wb] = \
        (unsigned char)(__builtin_amdgcn_cvt_pk_fp8_f32(16.f * h0, 16.f * h0, 0, 0) & 0xff); \
    XTRA \
    asm volatile("s_waitcnt lgkmcnt(0)" ::: "memory"); \
    __builtin_amdgcn_s_barrier(); \
}

  for (int g = 0; g < 128; ++g){
    STEP(0, 0,    { })
    STEP(1, 4096, { })
    STEP(2, 0,    { })
    // step 3: rebuild xp accs for group g+1 (register-only, after the h write ->
    // off the serial chain), then prefetch x for group g+2.
    STEP(3, 4096, {
      xZ = MFS(xfa, Pz, SP4(bz)); xR = MFS(xfa, Pr, SP4(br)); xX = MFS(xfa, Ph, SP4(bx));
      xfa = XLD(tok2);
      tok2 = tokens[tbx + tix(4 * (g + 3) + srow)];
    })
  }
#undef STEP
#undef MFS
#undef XLD
#undef SP4

  // final state -> hbuf[512][256]: every lane owns (batch l4, col c) exactly once
  hbuf[(size_t)(grp * 4 + l4) * 256 + dir * 128 + c] = h0;
}

// ---------------- head: sigmoid(hcat @ Wd + bd) ----------------
__global__ void head_k(const float* __restrict__ hbuf, const float* __restrict__ Wd,
                       const float* __restrict__ bd, float* __restrict__ out){
  const int wid = threadIdx.x >> 6, lane = threadIdx.x & 63;
  const int b = blockIdx.x * 4 + wid;
  const float* hr = hbuf + (size_t)b * 256;
  float s = 0.f;
#pragma unroll
  for (int j = 0; j < 4; ++j){ const int k = j * 64 + lane; s += hr[k] * Wd[k]; }
#pragma unroll
  for (int off = 32; off > 0; off >>= 1) s += __shfl_down(s, off);
  if (lane == 0) out[b] = 1.f / (1.f + __expf(-(s + bd[0])));
}

extern "C" void kernel_launch(void* const* d_in, const int* in_sizes, int n_in,
                              void* d_out, int out_size, void* d_ws, size_t ws_size,
                              hipStream_t stream){
  const int*   tokens = (const int*)  d_in[0];
  const float* emb    = (const float*)d_in[1];
  const float* Wf     = (const float*)d_in[2];
  const float* Uf     = (const float*)d_in[3];
  const float* bf_    = (const float*)d_in[4];
  const float* Wb     = (const float*)d_in[5];
  const float* Ub     = (const float*)d_in[6];
  const float* bb_    = (const float*)d_in[7];
  const float* Wd     = (const float*)d_in[8];
  const float* bd     = (const float*)d_in[9];
  float* out = (float*)d_out;

  unsigned char* embq = (unsigned char*)d_ws;                        // 6.4 MB fp8 table
  float* hbuf = (float*)((char*)d_ws + (size_t)VOC * HD);            // 512 KB

  const int n4 = VOC * HD / 4;
  emb_cvt8<<<(n4 + 255) / 256, 256, 0, stream>>>(emb, (int*)embq, n4);
  gru_scan<<<256, 512, 0, stream>>>(tokens, embq, Wf, Uf, bf_, Wb, Ub, bb_, hbuf);
  head_k<<<128, 256, 0, stream>>>(hbuf, Wd, bd, out);
}

// Round 12
// 170.747 us; speedup vs baseline: 2.2065x; 1.0368x over previous
//
#include <hip/hip_runtime.h>

#define TLEN 512
#define HD 128
#define VOC 50000

typedef float fvec4 __attribute__((ext_vector_type(4)));   // f32 MFMA accumulator
typedef int   ivec4 __attribute__((ext_vector_type(4)));   // 16B LDS read
typedef int   ivec8 __attribute__((ext_vector_type(8)));   // 32 fp8 = f8f6f4 operand

__device__ __forceinline__ float fsig(float a){
  return __builtin_amdgcn_rcpf(1.f + __builtin_amdgcn_exp2f(-1.44269504f * a));
}

// ---------------- emb fp32 -> fp8 e4m3 (x16 scale) table ----------------
__global__ void emb_cvt8(const float* __restrict__ emb, int* __restrict__ out, int n4){
  int i = blockIdx.x * blockDim.x + threadIdx.x;
  if (i < n4){
    float4 v = *(const float4*)(emb + (size_t)i * 4);
    int p = __builtin_amdgcn_cvt_pk_fp8_f32(16.f * v.x, 16.f * v.y, 0, 0);
    p     = __builtin_amdgcn_cvt_pk_fp8_f32(16.f * v.z, 16.f * v.w, p, 1);
    out[i] = p;
  }
}

// ---------------- persistent bidirectional GRU scan: 8-wave x 1 col-tile ----------------
// 256 blocks = 256 CUs (96KB LDS pin): 0..127 fwd, 128..255 bwd; 4 batches each
// (tile rows 0,4,8,12). 512 threads = 8 waves; wave w owns gate cols [w*16,w*16+16).
// Per wave per step: 2 ds_read_b128 (h fp8) + 1 woven xp MFS (in the ds_read
// latency shadow; E/O double acc set, x-frags dbuf'd 4 steps ahead) + 3 rec MFS
// + 1 gate/lane + 1-byte h write + 1 barrier. All fp8 stored x16 with e8m0
// block-scale 2^-4 per side (exact net 1). h master kept as 16*h (exact scaling,
// bit-identical) so the fp8 write needs no muls.
__global__ __launch_bounds__(512, 2) void gru_scan(
    const int* __restrict__ tokens, const unsigned char* __restrict__ embq,
    const float* __restrict__ Wf, const float* __restrict__ Uf, const float* __restrict__ bfv,
    const float* __restrict__ Wb, const float* __restrict__ Ub, const float* __restrict__ bbv,
    float* __restrict__ hbuf)
{
  const int tid  = threadIdx.x;
  const int wid  = tid >> 6, lane = tid & 63;
  const int l15  = lane & 15, l4 = lane >> 4;
  const int dir  = blockIdx.x >> 7, grp = blockIdx.x & 127;
  const int c    = wid * 16 + l15;                   // this lane's single gate column

  const float* __restrict__ W  = dir ? Wb : Wf;
  const float* __restrict__ U  = dir ? Ub : Uf;
  const float* __restrict__ bv = dir ? bbv : bfv;

  // claim 96KB -> 1 block/CU; used: 8KB h fp8 dbuf (16 rows x 144B at 0 / 4096)
  __shared__ __attribute__((aligned(16))) unsigned char hl[98304];

  // fp8 B-frags (x16): lane (l4,l15): col = chosen, k = l4*32 + j
  auto pack8 = [&](const float* M, int col)->ivec8{
    ivec8 q;
#pragma unroll
    for (int w = 0; w < 8; ++w){
      const int k0 = l4 * 32 + w * 4;
      int v = __builtin_amdgcn_cvt_pk_fp8_f32(16.f*M[(k0+0)*384 + col], 16.f*M[(k0+1)*384 + col], 0, 0);
      q[w]  = __builtin_amdgcn_cvt_pk_fp8_f32(16.f*M[(k0+2)*384 + col], 16.f*M[(k0+3)*384 + col], v, 1);
    }
    return q;
  };
  const ivec8 Qz = pack8(U, c), Qr = pack8(U, 128 + c), Qh = pack8(U, 256 + c);
  const ivec8 Pz = pack8(W, c), Pr = pack8(W, 128 + c), Ph = pack8(W, 256 + c);

  // biases: z/r (bi+bh) and hh-input folded into xp C (splat on use); hh-recurrent in gate
  const float bz = bv[c] + bv[384 + c];
  const float br = bv[128 + c] + bv[384 + 128 + c];
  const float bx = bv[256 + c];
  const float bu = bv[384 + 256 + c];
  const fvec4 ZF = {0.f,0.f,0.f,0.f};
#define SP4(b) ((fvec4){(b),(b),(b),(b)})

  for (int i = tid; i < 2048; i += 512) ((int*)hl)[i] = 0;   // zero both h buffers
  float h16 = 0.f;                                  // 16*h[batch l4][c] fp32 master

  // x A-frag: tile row l15 = (batch l15>>2, step l15&3)
  const int  brow = l15 >> 2, srow = l15 & 3;
  const long tbx  = (long)(grp * 4 + brow) * TLEN;
  const int  tb0  = dir ? (TLEN - 1) : 0, tsg = dir ? -1 : 1;
  auto tix = [&](int t){ t = (t > TLEN - 1) ? (TLEN - 1) : t; return tb0 + tsg * t; };
#define XLD(tok) (*(const ivec8*)(embq + (size_t)(tok) * HD + l4 * 32))
#define MFS(A, B, C) __builtin_amdgcn_mfma_scale_f32_16x16x128_f8f6f4(A, B, C, 0, 0, 0, 0x7B7B7B7B, 0, 0x7B7B7B7B)

  // E/O xp accumulator sets: even groups gate from E while O(g+1) is woven, etc.
  fvec4 eZ, eR, eX, oZ = ZF, oR = ZF, oX = ZF;
  ivec8 xfa, xfb;
  {
    const int t0 = tokens[tbx + tix(srow)];
    ivec8 xf0 = XLD(t0);
    eZ = MFS(xf0, Pz, SP4(bz)); eR = MFS(xf0, Pr, SP4(br)); eX = MFS(xf0, Ph, SP4(bx));
    xfa = XLD(tokens[tbx + tix(4 + srow)]);          // x(group 1)
  }
  int tok2 = tokens[tbx + tix(8 + srow)];            // token(group 2)

  const int hrd = l15 * 144 + l4 * 32;               // h A-frag base (byte)
  const int wb  = (4 * l4) * 144 + c;                // 1-byte h write slot

  __syncthreads();

  // Step: ds_read issue -> XTOP (xp MFS / x prefetch, fills read latency) ->
  // 3 rec MFS -> gate -> h write -> lgkm drain -> barrier.
#define STEP(S, P, XZ, XR, XX, XTOP) { \
    ivec8 af; \
    *(ivec4*)&af       = *(const ivec4*)&hl[(P) + hrd]; \
    *((ivec4*)&af + 1) = *(const ivec4*)&hl[(P) + hrd + 16]; \
    XTOP \
    fvec4 aZ = MFS(af, Qz, ZF); \
    fvec4 aR = MFS(af, Qr, ZF); \
    fvec4 aU = MFS(af, Qh, ZF); \
    float z = fsig(XZ[S] + aZ[0]); \
    float r = fsig(XR[S] + aR[0]); \
    float a = XX[S] + r * (aU[0] + bu); a = fmaxf(a, -30.f); \
    float y = __builtin_amdgcn_exp2f(-2.88539008f * a); \
    float th16 = (16.f - 16.f * y) * __builtin_amdgcn_rcpf(1.f + y); \
    h16 = th16 + z * (h16 - th16); \
    hl[((P) ^ 4096) + wb] = \
        (unsigned char)(__builtin_amdgcn_cvt_pk_fp8_f32(h16, h16, 0, 0) & 0xff); \
    asm volatile("s_waitcnt lgkmcnt(0)" ::: "memory"); \
    __builtin_amdgcn_s_barrier(); \
}

  for (int g = 0; g < 128; g += 2){
    // even group g: gates from E; weave O(g+1) from xfa; prefetch xfb <- x(g+2)
    STEP(0, 0,    eZ,eR,eX, { oZ = MFS(xfa, Pz, SP4(bz));
                              xfb = XLD(tok2);
                              tok2 = tokens[tbx + tix(4 * (g + 3) + srow)]; })
    STEP(1, 4096, eZ,eR,eX, { oR = MFS(xfa, Pr, SP4(br)); })
    STEP(2, 0,    eZ,eR,eX, { oX = MFS(xfa, Ph, SP4(bx)); })
    STEP(3, 4096, eZ,eR,eX, { })
    // odd group g+1: gates from O; weave E(g+2) from xfb; prefetch xfa <- x(g+3)
    STEP(0, 0,    oZ,oR,oX, { eZ = MFS(xfb, Pz, SP4(bz));
                              xfa = XLD(tok2);
                              tok2 = tokens[tbx + tix(4 * (g + 4) + srow)]; })
    STEP(1, 4096, oZ,oR,oX, { eR = MFS(xfb, Pr, SP4(br)); })
    STEP(2, 0,    oZ,oR,oX, { eX = MFS(xfb, Ph, SP4(bx)); })
    STEP(3, 4096, oZ,oR,oX, { })
  }
#undef STEP
#undef MFS
#undef XLD
#undef SP4

  // final state -> hbuf[512][256]: every lane owns (batch l4, col c); h = h16/16
  hbuf[(size_t)(grp * 4 + l4) * 256 + dir * 128 + c] = h16 * 0.0625f;
}

// ---------------- head: sigmoid(hcat @ Wd + bd) ----------------
__global__ void head_k(const float* __restrict__ hbuf, const float* __restrict__ Wd,
                       const float* __restrict__ bd, float* __restrict__ out){
  const int wid = threadIdx.x >> 6, lane = threadIdx.x & 63;
  const int b = blockIdx.x * 4 + wid;
  const float* hr = hbuf + (size_t)b * 256;
  float s = 0.f;
#pragma unroll
  for (int j = 0; j < 4; ++j){ const int k = j * 64 + lane; s += hr[k] * Wd[k]; }
#pragma unroll
  for (int off = 32; off > 0; off >>= 1) s += __shfl_down(s, off);
  if (lane == 0) out[b] = 1.f / (1.f + __expf(-(s + bd[0])));
}

extern "C" void kernel_launch(void* const* d_in, const int* in_sizes, int n_in,
                              void* d_out, int out_size, void* d_ws, size_t ws_size,
                              hipStream_t stream){
  const int*   tokens = (const int*)  d_in[0];
  const float* emb    = (const float*)d_in[1];
  const float* Wf     = (const float*)d_in[2];
  const float* Uf     = (const float*)d_in[3];
  const float* bf_    = (const float*)d_in[4];
  const float* Wb     = (const float*)d_in[5];
  const float* Ub     = (const float*)d_in[6];
  const float* bb_    = (const float*)d_in[7];
  const float* Wd     = (const float*)d_in[8];
  const float* bd     = (const float*)d_in[9];
  float* out = (float*)d_out;

  unsigned char* embq = (unsigned char*)d_ws;                        // 6.4 MB fp8 table
  float* hbuf = (float*)((char*)d_ws + (size_t)VOC * HD);            // 512 KB

  const int n4 = VOC * HD / 4;
  emb_cvt8<<<(n4 + 255) / 256, 256, 0, stream>>>(emb, (int*)embq, n4);
  gru_scan<<<256, 512, 0, stream>>>(tokens, embq, Wf, Uf, bf_, Wb, Ub, bb_, hbuf);
  head_k<<<128, 256, 0, stream>>>(hbuf, Wd, bd, out);
}